// Round 6
// baseline (342.793 us; speedup 1.0000x reference)
//
#include <hip/hip_runtime.h>

#define NQ 16

// R5 post-mortem: both #pragma-unroll (R1-R3) and frontend-constant indices
// via template sfor (R5) left s[64] as a scratch alloca: VGPR pinned at 64,
// 660 MB/dispatch spill traffic, 227 us. Root cause is the array/lambda alloca
// path never getting promoted. This version has NO aggregates and NO lambdas:
// 64 named scalars + token-pasted macro codegen -> plain mem2reg promotion.

// complex multiply: (rr,ri) = (ar,ai)*(br,bi)  (safe for aliasing)
#define CMUL(rr, ri, ar, ai, br, bi) do { \
  const float _tr = (ar)*(br) - (ai)*(bi); \
  const float _ti = (ar)*(bi) + (ai)*(br); \
  (rr) = _tr; (ri) = _ti; } while (0)

// u_q = RY(p1[q]) * RX(xs[q]) * |0>:  u0=(cp*cx, sp*sx), u1=(sp*cx, -cp*sx)
#define MAKE_U(q, U0R, U0I, U1R, U1I) \
  float U0R, U0I, U1R, U1I; { \
    float sx_, cx_; __sincosf(xs[(q)] * 0.5f, &sx_, &cx_); \
    float sp_, cp_; __sincosf(p1[(q)] * 0.5f, &sp_, &cp_); \
    U0R = cp_ * cx_; U0I = sp_ * sx_; U1R = sp_ * cx_; U1I = -cp_ * sx_; }

// w[j] = u[j ^ sb]
#define SWAP_U(sb, U0R, U0I, U1R, U1I, W0R, W0I, W1R, W1I) \
  float W0R, W0I, W1R, W1I; { \
    W0R = (sb) ? (U1R) : (U0R); W0I = (sb) ? (U1I) : (U0I); \
    W1R = (sb) ? (U0R) : (U1R); W1I = (sb) ? (U0I) : (U1I); }

// one RY butterfly on named pair
#define BF(A, B) { const float xv_ = s##A, yv_ = s##B; \
  s##A = cs_ * xv_ + se_ * yv_; s##B = cs_ * yv_ - se_ * xv_; }

#define SET_K5 \
  BF(0,32) BF(1,33) BF(2,34) BF(3,35) BF(4,36) BF(5,37) BF(6,38) BF(7,39) \
  BF(8,40) BF(9,41) BF(10,42) BF(11,43) BF(12,44) BF(13,45) BF(14,46) BF(15,47) \
  BF(16,48) BF(17,49) BF(18,50) BF(19,51) BF(20,52) BF(21,53) BF(22,54) BF(23,55) \
  BF(24,56) BF(25,57) BF(26,58) BF(27,59) BF(28,60) BF(29,61) BF(30,62) BF(31,63)
#define SET_K4 \
  BF(0,16) BF(1,17) BF(2,18) BF(3,19) BF(4,20) BF(5,21) BF(6,22) BF(7,23) \
  BF(8,24) BF(9,25) BF(10,26) BF(11,27) BF(12,28) BF(13,29) BF(14,30) BF(15,31) \
  BF(32,48) BF(33,49) BF(34,50) BF(35,51) BF(36,52) BF(37,53) BF(38,54) BF(39,55) \
  BF(40,56) BF(41,57) BF(42,58) BF(43,59) BF(44,60) BF(45,61) BF(46,62) BF(47,63)
#define SET_K3 \
  BF(0,8) BF(1,9) BF(2,10) BF(3,11) BF(4,12) BF(5,13) BF(6,14) BF(7,15) \
  BF(16,24) BF(17,25) BF(18,26) BF(19,27) BF(20,28) BF(21,29) BF(22,30) BF(23,31) \
  BF(32,40) BF(33,41) BF(34,42) BF(35,43) BF(36,44) BF(37,45) BF(38,46) BF(39,47) \
  BF(48,56) BF(49,57) BF(50,58) BF(51,59) BF(52,60) BF(53,61) BF(54,62) BF(55,63)
#define SET_K2 \
  BF(0,4) BF(1,5) BF(2,6) BF(3,7) BF(8,12) BF(9,13) BF(10,14) BF(11,15) \
  BF(16,20) BF(17,21) BF(18,22) BF(19,23) BF(24,28) BF(25,29) BF(26,30) BF(27,31) \
  BF(32,36) BF(33,37) BF(34,38) BF(35,39) BF(40,44) BF(41,45) BF(42,46) BF(43,47) \
  BF(48,52) BF(49,53) BF(50,54) BF(51,55) BF(56,60) BF(57,61) BF(58,62) BF(59,63)
#define SET_K1 \
  BF(0,2) BF(1,3) BF(4,6) BF(5,7) BF(8,10) BF(9,11) BF(12,14) BF(13,15) \
  BF(16,18) BF(17,19) BF(20,22) BF(21,23) BF(24,26) BF(25,27) BF(28,30) BF(29,31) \
  BF(32,34) BF(33,35) BF(36,38) BF(37,39) BF(40,42) BF(41,43) BF(44,46) BF(45,47) \
  BF(48,50) BF(49,51) BF(52,54) BF(53,55) BF(56,58) BF(57,59) BF(60,62) BF(61,63)
#define SET_K0 \
  BF(0,1) BF(2,3) BF(4,5) BF(6,7) BF(8,9) BF(10,11) BF(12,13) BF(14,15) \
  BF(16,17) BF(18,19) BF(20,21) BF(22,23) BF(24,25) BF(26,27) BF(28,29) BF(30,31) \
  BF(32,33) BF(34,35) BF(36,37) BF(38,39) BF(40,41) BF(42,43) BF(44,45) BF(46,47) \
  BF(48,49) BF(50,51) BF(52,53) BF(54,55) BF(56,57) BF(58,59) BF(60,61) BF(62,63)

// RY stage: role-flip f absorbed as sign on sin
#define STAGE(q, KSET, f) { \
    float sn_, cs_; __sincosf(p2[(q)] * 0.5f, &sn_, &cs_); \
    const float se_ = (f) ? sn_ : -sn_; \
    KSET }

// one factor of the thread-fixed prefix product
#define PFAC(q, ab) { \
    float sx_, cx_; __sincosf(xs[(q)] * 0.5f, &sx_, &cx_); \
    float sp_, cp_; __sincosf(p1[(q)] * 0.5f, &sp_, &cp_); \
    const float u0r_ = cp_ * cx_, u0i_ = sp_ * sx_; \
    const float u1r_ = sp_ * cx_, u1i_ = -cp_ * sx_; \
    const float ar_ = (ab) ? u1r_ : u0r_; \
    const float ai_ = (ab) ? u1i_ : u0i_; \
    CMUL(Pr, Pi, Pr, Pi, ar_, ai_); }

// init tile: s{N0..N3} = (TA[ta]*TB[tb]) * g2[i0..i3], plane-selected component
#define GBLK(TA, TB, I0, I1, I2, I3, N0, N1, N2, N3) { \
    const float g1r_ = TAr##TA * TBr##TB - TAi##TA * TBi##TB; \
    const float g1i_ = TAr##TA * TBi##TB + TAi##TA * TBr##TB; \
    s##N0 = plane ? (g1r_ * g2i##I0 + g1i_ * g2r##I0) : (g1r_ * g2r##I0 - g1i_ * g2i##I0); \
    s##N1 = plane ? (g1r_ * g2i##I1 + g1i_ * g2r##I1) : (g1r_ * g2r##I1 - g1i_ * g2i##I1); \
    s##N2 = plane ? (g1r_ * g2i##I2 + g1i_ * g2r##I2) : (g1r_ * g2r##I2 - g1i_ * g2i##I2); \
    s##N3 = plane ? (g1r_ * g2i##I3 + g1i_ * g2r##I3) : (g1r_ * g2r##I3 - g1i_ * g2i##I3); }

// T1: in-wave lane<->slot transpose, XOR-swizzled (writes b32, reads b128)
#define T1WRITE(S0,S1,S2,S3,S4,S5,S6,S7,S8,S9,S10,S11,S12,S13,S14,S15) \
  lds[waveBase +   0 + lxa] = S0;  lds[waveBase +  64 + lxa] = S1; \
  lds[waveBase + 128 + lxa] = S2;  lds[waveBase + 192 + lxa] = S3; \
  lds[waveBase + 256 + lxb] = S4;  lds[waveBase + 320 + lxb] = S5; \
  lds[waveBase + 384 + lxb] = S6;  lds[waveBase + 448 + lxb] = S7; \
  lds[waveBase + 512 + lxc] = S8;  lds[waveBase + 576 + lxc] = S9; \
  lds[waveBase + 640 + lxc] = S10; lds[waveBase + 704 + lxc] = S11; \
  lds[waveBase + 768 + lxd] = S12; lds[waveBase + 832 + lxd] = S13; \
  lds[waveBase + 896 + lxd] = S14; lds[waveBase + 960 + lxd] = S15;

#define T1READ(OFS, S0, S1, S2, S3) { \
    const float4 v_ = *reinterpret_cast<const float4*>(&lds[rdbase + ((xb_ + (OFS)) ^ kkm12)]); \
    S0 = v_.x; S1 = v_.y; S2 = v_.z; S3 = v_.w; }

#define T1BLOCK(D, S0,S1,S2,S3,S4,S5,S6,S7,S8,S9,S10,S11,S12,S13,S14,S15) { \
    __syncthreads(); \
    T1WRITE(S0,S1,S2,S3,S4,S5,S6,S7,S8,S9,S10,S11,S12,S13,S14,S15) \
    __syncthreads(); \
    const int xb_ = 16 * ((D) ^ bp); \
    T1READ(0, S0, S1, S2, S3) T1READ(4, S4, S5, S6, S7) \
    T1READ(8, S8, S9, S10, S11) T1READ(12, S12, S13, S14, S15) }

// T2: cross-wave swap; write slot m at (m*64)^mx64 (undoes reg-xor invariant),
// read back clean: reg == actual slot afterwards.
#define T2BLOCK(S0,S1,S2,S3,S4,S5,S6,S7,S8,S9,S10,S11,S12,S13,S14,S15) { \
    __syncthreads(); \
    lds[wl + (  0 ^ mx64)] = S0;  lds[wl + ( 64 ^ mx64)] = S1; \
    lds[wl + (128 ^ mx64)] = S2;  lds[wl + (192 ^ mx64)] = S3; \
    lds[wl + (256 ^ mx64)] = S4;  lds[wl + (320 ^ mx64)] = S5; \
    lds[wl + (384 ^ mx64)] = S6;  lds[wl + (448 ^ mx64)] = S7; \
    lds[wl + (512 ^ mx64)] = S8;  lds[wl + (576 ^ mx64)] = S9; \
    lds[wl + (640 ^ mx64)] = S10; lds[wl + (704 ^ mx64)] = S11; \
    lds[wl + (768 ^ mx64)] = S12; lds[wl + (832 ^ mx64)] = S13; \
    lds[wl + (896 ^ mx64)] = S14; lds[wl + (960 ^ mx64)] = S15; \
    __syncthreads(); \
    S0  = lds[        wl2]; S1  = lds[ 1024 + wl2]; \
    S2  = lds[ 2048 + wl2]; S3  = lds[ 3072 + wl2]; \
    S4  = lds[ 4096 + wl2]; S5  = lds[ 5120 + wl2]; \
    S6  = lds[ 6144 + wl2]; S7  = lds[ 7168 + wl2]; \
    S8  = lds[ 8192 + wl2]; S9  = lds[ 9216 + wl2]; \
    S10 = lds[10240 + wl2]; S11 = lds[11264 + wl2]; \
    S12 = lds[12288 + wl2]; S13 = lds[13312 + wl2]; \
    S14 = lds[14336 + wl2]; S15 = lds[15360 + wl2]; }

// partial Walsh fold over one 16-slot group
#define MEAS(AL, BE, GA, DE, EP, S0,S1,S2,S3,S4,S5,S6,S7,S8,S9,S10,S11,S12,S13,S14,S15) { \
    const float q0_=S0*S0, q1_=S1*S1, q2_=S2*S2, q3_=S3*S3; \
    const float q4_=S4*S4, q5_=S5*S5, q6_=S6*S6, q7_=S7*S7; \
    const float q8_=S8*S8, q9_=S9*S9, q10_=S10*S10, q11_=S11*S11; \
    const float q12_=S12*S12, q13_=S13*S13, q14_=S14*S14, q15_=S15*S15; \
    const float t0_=q0_+q1_, u0_=q0_-q1_, t1_=q2_+q3_, u1_=q2_-q3_; \
    const float t2_=q4_+q5_, u2_=q4_-q5_, t3_=q6_+q7_, u3_=q6_-q7_; \
    const float t4_=q8_+q9_, u4_=q8_-q9_, t5_=q10_+q11_, u5_=q10_-q11_; \
    const float t6_=q12_+q13_, u6_=q12_-q13_, t7_=q14_+q15_, u7_=q14_-q15_; \
    const float ts0_=t0_+t1_, td0_=t0_-t1_, ud0_=u0_-u1_; \
    const float ts1_=t2_+t3_, td1_=t2_-t3_, ud1_=u2_-u3_; \
    const float ts2_=t4_+t5_, td2_=t4_-t5_, ud2_=u4_-u5_; \
    const float ts3_=t6_+t7_, td3_=t6_-t7_, ud3_=u6_-u7_; \
    const float tss0_=ts0_+ts1_, tsd0_=ts0_-ts1_, tdd0_=td0_-td1_, udd0_=ud0_-ud1_; \
    const float tss1_=ts2_+ts3_, tsd1_=ts2_-ts3_, tdd1_=td2_-td3_, udd1_=ud2_-ud3_; \
    AL = tss0_ + tss1_; BE = tss0_ - tss1_; GA = tsd0_ - tsd1_; \
    DE = tdd0_ - tdd1_; EP = udd0_ - udd1_; }

// 96 KB LDS pad -> 1 block/CU; waves_per_eu(4,4) -> 128-VGPR budget.
__global__
__attribute__((amdgpu_flat_work_group_size(1024, 1024)))
__attribute__((amdgpu_waves_per_eu(4, 4)))
void qsim_kernel(const float* __restrict__ x, const float* __restrict__ params,
                 float* __restrict__ out) {
  const int sample = blockIdx.x;
  const int tid = threadIdx.x;
  const int w = tid >> 6;   // wave 0..15
  const int l = tid & 63;   // lane 0..63

  const int w3 = (w >> 3) & 1, w2b = (w >> 2) & 1, w1b = (w >> 1) & 1, w0b = w & 1;
  const int l5 = (l >> 5) & 1, l4 = (l >> 4) & 1, l3 = (l >> 3) & 1;
  const int l2 = (l >> 2) & 1, l1 = (l >> 1) & 1, l0 = l & 1;

  __shared__ __align__(16) float lds[24576];  // 96 KB (64 KB used; pad = occupancy pin)

  const float* xs = x + sample * NQ;
  const float* p1 = params;       // layer-1 RY angles
  const float* p2 = params + NQ;  // layer-2 RY angles

  // M^{-1} select bits for the prefix product (qubits 2..9).
  // Init layout: i = [w(4) | l(6) | slot(6)], qubit q <-> index bit 15-q.
  const int a_2 = w2b ^ w1b, a_3 = w1b ^ w0b, a_4 = w0b ^ l5, a_5 = l5 ^ l4;
  const int a_6 = l4 ^ l3,  a_7 = l3 ^ l2,  a_8 = l2 ^ l1,  a_9 = l1 ^ l0;

  // loop-invariant addressing
  const int waveBase = w << 10;
  const int bp = l >> 4;
  const int kk = l & 15;
  const int kkm12 = kk & 12;
  const int rdbase = waveBase + kk * 64;
  const int lxa = l, lxb = l ^ 4, lxc = l ^ 8, lxd = l ^ 12;
  const int wl = waveBase + l;          // (w<<10) + l
  const int wl2 = (w << 6) + l;
  const int mx64 = (l & 48) << 4;       // ((l5<<3)^(l4<<2))*64

  float acc = 0.0f;   // wave w, lane 0 accumulates <Z_w> across planes

  for (int plane = 0; plane < 2; ++plane) {
    float s0,s1,s2,s3,s4,s5,s6,s7,s8,s9,s10,s11,s12,s13,s14,s15,
          s16,s17,s18,s19,s20,s21,s22,s23,s24,s25,s26,s27,s28,s29,s30,s31,
          s32,s33,s34,s35,s36,s37,s38,s39,s40,s41,s42,s43,s44,s45,s46,s47,
          s48,s49,s50,s51,s52,s53,s54,s55,s56,s57,s58,s59,s60,s61,s62,s63;

    // ---------------- init: ring-1-permuted product state ----------------
    float Pr = 1.0f, Pi = 0.0f;
    PFAC(2, a_2) PFAC(3, a_3) PFAC(4, a_4) PFAC(5, a_5)
    PFAC(6, a_6) PFAC(7, a_7) PFAC(8, a_8) PFAC(9, a_9)

    // Register-slot invariant pre-T2: actual_slot = reg ^ (l5<<5 | l4<<4).
    float TAr0,TAr1,TAr2,TAr3, TAi0,TAi1,TAi2,TAi3;
    float TBr0,TBr1,TBr2,TBr3, TBi0,TBi1,TBi2,TBi3;
    float g2r0,g2r1,g2r2,g2r3,g2r4,g2r5,g2r6,g2r7;
    float g2i0,g2i1,g2i2,g2i3,g2i4,g2i5,g2i6,g2i7;
    {
      MAKE_U(10, uA0r, uA0i, uA1r, uA1i);
      SWAP_U(l0 ^ l5, uA0r, uA0i, uA1r, uA1i, wA0r, wA0i, wA1r, wA1i);
      MAKE_U(11, uB0r, uB0i, uB1r, uB1i);
      SWAP_U(l5 ^ l4, uB0r, uB0i, uB1r, uB1i, wB0r, wB0i, wB1r, wB1i);
      // TA[h5*2+h4] = wA[h5] * wB[h5^h4]
      CMUL(TAr0, TAi0, wA0r, wA0i, wB0r, wB0i);
      CMUL(TAr1, TAi1, wA0r, wA0i, wB1r, wB1i);
      CMUL(TAr2, TAi2, wA1r, wA1i, wB1r, wB1i);
      CMUL(TAr3, TAi3, wA1r, wA1i, wB0r, wB0i);
    }
    {
      MAKE_U(12, uC0r, uC0i, uC1r, uC1i);
      SWAP_U(l4, uC0r, uC0i, uC1r, uC1i, wC0r, wC0i, wC1r, wC1i);
      MAKE_U(13, uD0r, uD0i, uD1r, uD1i);
      // TB[x*2+y] = wC[x]*u13[y],  x = h4^h3, y = h3^h2
      CMUL(TBr0, TBi0, wC0r, wC0i, uD0r, uD0i);
      CMUL(TBr1, TBi1, wC0r, wC0i, uD1r, uD1i);
      CMUL(TBr2, TBi2, wC1r, wC1i, uD0r, uD0i);
      CMUL(TBr3, TBi3, wC1r, wC1i, uD1r, uD1i);
    }
    {
      MAKE_U(0, uE0r, uE0i, uE1r, uE1i);
      SWAP_U(w3, uE0r, uE0i, uE1r, uE1i, wD0r, wD0i, wD1r, wD1i);
      MAKE_U(1, uF0r, uF0i, uF1r, uF1i);
      SWAP_U(w3 ^ w2b, uF0r, uF0i, uF1r, uF1i, wE0r, wE0i, wE1r, wE1i);
      float d0r0, d0i0, d0r1, d0i1;
      CMUL(d0r0, d0i0, wD0r, wD0i, wE0r, wE0i);
      CMUL(d0r0, d0i0, d0r0, d0i0, Pr, Pi);
      CMUL(d0r1, d0i1, wD1r, wD1i, wE1r, wE1i);
      CMUL(d0r1, d0i1, d0r1, d0i1, Pr, Pi);
      MAKE_U(15, uG0r, uG0i, uG1r, uG1i);
      float d1r0, d1i0, d1r1, d1i1, d1r2, d1i2, d1r3, d1i3;  // d1[h1*2+h0] = u15[h1^h0]*d0[h0]
      CMUL(d1r0, d1i0, uG0r, uG0i, d0r0, d0i0);
      CMUL(d1r1, d1i1, uG1r, uG1i, d0r1, d0i1);
      CMUL(d1r2, d1i2, uG1r, uG1i, d0r0, d0i0);
      CMUL(d1r3, d1i3, uG0r, uG0i, d0r1, d0i1);
      MAKE_U(14, uH0r, uH0i, uH1r, uH1i);
      // g2[h2*4+h1*2+h0] = u14[h2^h1]*d1[h1*2+h0]
      CMUL(g2r0, g2i0, uH0r, uH0i, d1r0, d1i0);
      CMUL(g2r1, g2i1, uH0r, uH0i, d1r1, d1i1);
      CMUL(g2r2, g2i2, uH1r, uH1i, d1r2, d1i2);
      CMUL(g2r3, g2i3, uH1r, uH1i, d1r3, d1i3);
      CMUL(g2r4, g2i4, uH1r, uH1i, d1r0, d1i0);
      CMUL(g2r5, g2i5, uH1r, uH1i, d1r1, d1i1);
      CMUL(g2r6, g2i6, uH0r, uH0i, d1r2, d1i2);
      CMUL(g2r7, g2i7, uH0r, uH0i, d1r3, d1i3);
    }
    // g = h5h4h3h2; ta = h5*2+h4, tb = ((h4^h3)<<1)|(h3^h2), i7 = (h2<<2)|t
    GBLK(0, 0, 0, 1, 2, 3,  0,  1,  2,  3)
    GBLK(0, 1, 4, 5, 6, 7,  4,  5,  6,  7)
    GBLK(0, 3, 0, 1, 2, 3,  8,  9, 10, 11)
    GBLK(0, 2, 4, 5, 6, 7, 12, 13, 14, 15)
    GBLK(1, 2, 0, 1, 2, 3, 16, 17, 18, 19)
    GBLK(1, 3, 4, 5, 6, 7, 20, 21, 22, 23)
    GBLK(1, 1, 0, 1, 2, 3, 24, 25, 26, 27)
    GBLK(1, 0, 4, 5, 6, 7, 28, 29, 30, 31)
    GBLK(2, 0, 0, 1, 2, 3, 32, 33, 34, 35)
    GBLK(2, 1, 4, 5, 6, 7, 36, 37, 38, 39)
    GBLK(2, 3, 0, 1, 2, 3, 40, 41, 42, 43)
    GBLK(2, 2, 4, 5, 6, 7, 44, 45, 46, 47)
    GBLK(3, 2, 0, 1, 2, 3, 48, 49, 50, 51)
    GBLK(3, 3, 4, 5, 6, 7, 52, 53, 54, 55)
    GBLK(3, 1, 0, 1, 2, 3, 56, 57, 58, 59)
    GBLK(3, 0, 4, 5, 6, 7, 60, 61, 62, 63)

    // ---------------- set 1: qubits 10..15 (slot bits 5..0) ----------------
    STAGE(10, SET_K5, l5) STAGE(11, SET_K4, l4) STAGE(12, SET_K3, 0)
    STAGE(13, SET_K2, 0)  STAGE(14, SET_K1, 0)  STAGE(15, SET_K0, 0)

    // ---------------- T1: in-wave lane<->slot transpose ----------------
    T1BLOCK(0, s0,s1,s2,s3,s4,s5,s6,s7,s8,s9,s10,s11,s12,s13,s14,s15)
    T1BLOCK(1, s16,s17,s18,s19,s20,s21,s22,s23,s24,s25,s26,s27,s28,s29,s30,s31)
    T1BLOCK(2, s32,s33,s34,s35,s36,s37,s38,s39,s40,s41,s42,s43,s44,s45,s46,s47)
    T1BLOCK(3, s48,s49,s50,s51,s52,s53,s54,s55,s56,s57,s58,s59,s60,s61,s62,s63)

    // ---------------- set 2: qubits 4..9 (slot bits 5..0) ----------------
    STAGE(4, SET_K5, l5) STAGE(5, SET_K4, l4) STAGE(6, SET_K3, 0)
    STAGE(7, SET_K2, 0)  STAGE(8, SET_K1, 0)  STAGE(9, SET_K0, 0)

    // ---------------- T2: cross-wave swap (wave bits <-> slot bits 5..2) ----------------
    T2BLOCK(s0,s4,s8,s12,s16,s20,s24,s28,s32,s36,s40,s44,s48,s52,s56,s60)
    T2BLOCK(s1,s5,s9,s13,s17,s21,s25,s29,s33,s37,s41,s45,s49,s53,s57,s61)
    T2BLOCK(s2,s6,s10,s14,s18,s22,s26,s30,s34,s38,s42,s46,s50,s54,s58,s62)
    T2BLOCK(s3,s7,s11,s15,s19,s23,s27,s31,s35,s39,s43,s47,s51,s55,s59,s63)

    // ---------------- set 3: qubits 0..3 (slot bits 5..2) ----------------
    STAGE(0, SET_K5, 0) STAGE(1, SET_K4, 0) STAGE(2, SET_K3, 0) STAGE(3, SET_K2, 0)

    // ---------------- measurement: partial Walsh fold ----------------
    // Final layout: qubit bits: b0..b3 = slot5..2, b4..b7 = w3..w0, b8,b9 = slot1,0,
    // b10..b15 = l5..l0. Ring-2 absorbed: mask_q = prefix parity.
    float alpha0, beta0, gamma0, delta0, eps0;
    float alpha1, beta1, gamma1, delta1, eps1;
    float alpha2, beta2, gamma2, delta2, eps2;
    float alpha3, beta3, gamma3, delta3, eps3;
    MEAS(alpha0, beta0, gamma0, delta0, eps0,
         s0,s1,s2,s3,s4,s5,s6,s7,s8,s9,s10,s11,s12,s13,s14,s15)
    MEAS(alpha1, beta1, gamma1, delta1, eps1,
         s16,s17,s18,s19,s20,s21,s22,s23,s24,s25,s26,s27,s28,s29,s30,s31)
    MEAS(alpha2, beta2, gamma2, delta2, eps2,
         s32,s33,s34,s35,s36,s37,s38,s39,s40,s41,s42,s43,s44,s45,s46,s47)
    MEAS(alpha3, beta3, gamma3, delta3, eps3,
         s48,s49,s50,s51,s52,s53,s54,s55,s56,s57,s58,s59,s60,s61,s62,s63)

    const float TA_ = (alpha0 - alpha1) - (alpha2 - alpha3);
    const float TB_ = (beta0  - beta1)  - (beta2  - beta3);
    const float TC_ = (gamma0 - gamma1) - (gamma2 - gamma3);
    const float TD_ = (delta0 - delta1) - (delta2 - delta3);
    const float TE_ = (eps0   - eps1)   - (eps2   - eps3);
    const float TF_ = (eps0   - eps1)   + (eps2   - eps3);

    const int pw1 = w3, pw2 = w3 ^ w2b, pw3 = w3 ^ w2b ^ w1b, pw4 = w3 ^ w2b ^ w1b ^ w0b;
    const int pl1 = l5, pl2 = pl1 ^ l4, pl3 = pl2 ^ l3, pl4 = pl3 ^ l2, pl5 = pl4 ^ l1, pl6 = pl5 ^ l0;

    const float part0  = (pw4 ^ pl6) ? -TF_ : TF_;
    const float part1  = TA_;
    const float part2  = TB_;
    const float part3  = TC_;
    const float part4  = pw1 ? -TC_ : TC_;
    const float part5  = pw2 ? -TC_ : TC_;
    const float part6  = pw3 ? -TC_ : TC_;
    const float part7  = pw4 ? -TC_ : TC_;
    const float part8  = pw4 ? -TD_ : TD_;
    const float part9  = pw4 ? -TE_ : TE_;
    const float part10 = (pw4 ^ pl1) ? -TE_ : TE_;
    const float part11 = (pw4 ^ pl2) ? -TE_ : TE_;
    const float part12 = (pw4 ^ pl3) ? -TE_ : TE_;
    const float part13 = (pw4 ^ pl4) ? -TE_ : TE_;
    const float part14 = (pw4 ^ pl5) ? -TE_ : TE_;
    const float part15 = (pw4 ^ pl6) ? -TE_ : TE_;

    // ---------------- block reduction: wave q reduces output q ----------------
    __syncthreads();
    lds[wl +   0] = part0;  lds[wl +  64] = part1;
    lds[wl + 128] = part2;  lds[wl + 192] = part3;
    lds[wl + 256] = part4;  lds[wl + 320] = part5;
    lds[wl + 384] = part6;  lds[wl + 448] = part7;
    lds[wl + 512] = part8;  lds[wl + 576] = part9;
    lds[wl + 640] = part10; lds[wl + 704] = part11;
    lds[wl + 768] = part12; lds[wl + 832] = part13;
    lds[wl + 896] = part14; lds[wl + 960] = part15;
    __syncthreads();
    float v = 0.0f;
    #pragma unroll
    for (int w2_ = 0; w2_ < 16; ++w2_)
      v += lds[(w2_ << 10) + wl2];
    #pragma unroll
    for (int off = 32; off >= 1; off >>= 1)
      v += __shfl_xor(v, off, 64);
    acc += v;
  }

  if (l == 0) out[sample * NQ + w] = acc;
}

extern "C" void kernel_launch(void* const* d_in, const int* in_sizes, int n_in,
                              void* d_out, int out_size, void* d_ws, size_t ws_size,
                              hipStream_t stream) {
  (void)in_sizes; (void)n_in; (void)d_ws; (void)ws_size; (void)out_size;
  const float* x = (const float*)d_in[0];       // (512, 16) fp32
  const float* params = (const float*)d_in[1];  // (32,) fp32
  float* out = (float*)d_out;                   // (512, 16) fp32
  hipLaunchKernelGGL(qsim_kernel, dim3(512), dim3(1024), 0, stream, x, params, out);
}

// Round 7
// 56.746 us; speedup vs baseline: 6.0408x; 6.0408x over previous
//
#include <hip/hip_runtime.h>

// R6 post-mortem: the 64-VGPR budget is immovable from source (3 promotion
// strategies x 3 occupancy attributes, all VGPR_Count==64, ~660 MB spill/scratch
// traffic = the entire runtime). This round replaces the 2^16-amplitude state
// evolution with an exact transfer-matrix contraction:
//
//   phi(b) = prod_q u_q[a_q(b)],  a_0=b0^b15, a_1=b0^b1^b15, a_q=b_{q-1}^b_q
//   (ring-1 fully absorbed; verified against the R1-R6 passing kernel's init)
//   <Z_q> = <phi| RY2^T Zhat_q RY2 |phi>,  Zhat_q = Z_{0..q} (q>=1), Z_{1..15} (q=0)
//   (ring-2 conjugation; verified against the passing kernel's part[] masks)
//
// Pair variables p_j=(b_j,b'_j) in {0..3}; with c = b0^b15 the factor graph is a
// ring of 16 4x4 complex transfer matrices: <Z_q> = Tr(A_1...A_15 A_cl).
// One thread per (sample, q): 15 row-updates of a 4-complex row + closure.
// Lane (q, row r): rows of M evolve independently; quad-reduce at the end.
// ~40 VGPRs, no LDS, no arrays, no barriers. 8192 threads total.

// site update for chain position K (K = literal 1..15):
// row <- row * A_K,  A_K[p,p'] = u_K[v^w] * conj(u_K)[v'^w'] * D_K[p']
#define SITE(K) { \
    const float hx = xs[K] * 0.5f; \
    const float cx = __cosf(hx), sx = __sinf(hx); \
    const float hp = p1v[K] * 0.5f; \
    const float cp = __cosf(hp), sp = __sinf(hp); \
    const float u0r = cp*cx, u0i = sp*sx, u1r = sp*cx, u1i = -cp*sx; \
    /* t[v,w'] = sum_{v'} m[(v,v')] * conj(u[v'^w']) */ \
    const float t00r = m0r*u0r + m0i*u0i + m1r*u1r + m1i*u1i; \
    const float t00i = m0i*u0r - m0r*u0i + m1i*u1r - m1r*u1i; \
    const float t01r = m0r*u1r + m0i*u1i + m1r*u0r + m1i*u0i; \
    const float t01i = m0i*u1r - m0r*u1i + m1i*u0r - m1r*u0i; \
    const float t10r = m2r*u0r + m2i*u0i + m3r*u1r + m3i*u1i; \
    const float t10i = m2i*u0r - m2r*u0i + m3i*u1r - m3r*u1i; \
    const float t11r = m2r*u1r + m2i*u1i + m3r*u0r + m3i*u0i; \
    const float t11i = m2i*u1r - m2r*u1i + m3i*u0r - m3r*u0i; \
    /* n[(w,w')] = sum_v t[v,w'] * u[v^w] */ \
    const float n00r = t00r*u0r - t00i*u0i + t10r*u1r - t10i*u1i; \
    const float n00i = t00r*u0i + t00i*u0r + t10r*u1i + t10i*u1r; \
    const float n01r = t01r*u0r - t01i*u0i + t11r*u1r - t11i*u1i; \
    const float n01i = t01r*u0i + t01i*u0r + t11r*u1i + t11i*u1r; \
    const float n10r = t00r*u1r - t00i*u1i + t10r*u0r - t10i*u0i; \
    const float n10i = t00r*u1i + t00i*u1r + t10r*u0i + t10i*u0r; \
    const float n11r = t01r*u1r - t01i*u1i + t11r*u0r - t11i*u0i; \
    const float n11i = t01r*u1i + t01i*u1r + t11r*u0i + t11i*u0r; \
    /* D_K[p'=(w,w')] = masked ? O[w',w] : delta;  O=[[C,-S],[-S,-C]] */ \
    const float th = p2v[K]; \
    const float Ck = __cosf(th), Sk = __sinf(th); \
    const bool mk = (q == 0) || ((K) <= q); \
    const float D00 = mk ?  Ck : 1.0f; \
    const float Dof = mk ? -Sk : 0.0f; \
    const float D11 = mk ? -Ck : 1.0f; \
    m0r = n00r*D00; m0i = n00i*D00; \
    m1r = n01r*Dof; m1i = n01i*Dof; \
    m2r = n10r*Dof; m2i = n10i*Dof; \
    m3r = n11r*D11; m3i = n11i*D11; \
  }

__global__ __launch_bounds__(256)
void qexp_kernel(const float* __restrict__ x, const float* __restrict__ params,
                 float* __restrict__ out) {
  const int lane = threadIdx.x & 63;
  const int q = lane >> 2;        // output qubit 0..15
  const int r = lane & 3;         // row of M (pair state p_0)
  const int sample = __builtin_amdgcn_readfirstlane(blockIdx.x * 4 + (threadIdx.x >> 6));

  const float* xs  = x + sample * 16;
  const float* p1v = params;        // layer-1 RY half-angle source
  const float* p2v = params + 16;   // layer-2 RY angles

  // M row r: 4 complex entries over p=(v,v'), index 2v+v'. Init: identity row.
  float m0r = (r == 0) ? 1.0f : 0.0f, m0i = 0.0f;
  float m1r = (r == 1) ? 1.0f : 0.0f, m1i = 0.0f;
  float m2r = (r == 2) ? 1.0f : 0.0f, m2i = 0.0f;
  float m3r = (r == 3) ? 1.0f : 0.0f, m3i = 0.0f;

  SITE(1)  SITE(2)  SITE(3)  SITE(4)  SITE(5)
  SITE(6)  SITE(7)  SITE(8)  SITE(9)  SITE(10)
  SITE(11) SITE(12) SITE(13) SITE(14) SITE(15)

  // Closure: A_cl[p15=(v,v'), p0=(w,w')] = D_0[(w^v, w'^v')] * u_0[w]*conj(u_0[w'])
  // Lane r supplies p0 = r: partial = sum_{p15} M[r,p15] * A_cl[p15, r].
  {
    const float hx = xs[0] * 0.5f;
    const float cx = __cosf(hx), sx = __sinf(hx);
    const float hp = p1v[0] * 0.5f;
    const float cp = __cosf(hp), sp = __sinf(hp);
    const float a0r = cp*cx, a0i = sp*sx;     // u_0[0]
    const float a1r = sp*cx, a1i = -cp*sx;    // u_0[1]
    const float th0 = p2v[0];
    const float C0 = __cosf(th0), S0 = __sinf(th0);
    const bool m0k = (q >= 1);                // site 0 masked iff q>=1
    const float d00 = m0k ?  C0 : 1.0f;
    const float dof = m0k ? -S0 : 0.0f;
    const float d11 = m0k ? -C0 : 1.0f;

    const int w  = r >> 1;
    const int wp = r & 1;
    // coef_p = d[(w^v), (w'^v')],  d(a,a') = (a!=a') ? dof : (a ? d11 : d00)
    const float ddiag0 = w ? d11 : d00;       // when alpha==alpha'==w
    const float ddiag1 = w ? d00 : d11;       // when alpha==alpha'==w^1
    const float cf0 = (w != wp) ? dof : ddiag0;          // p=(0,0): al=w, al'=wp
    const float cf1 = (w == wp) ? dof : ddiag0;          // p=(0,1): al=w, al'=wp^1
    const float cf2 = ((w ^ 1) != wp) ? dof : ddiag1;    // p=(1,0)
    const float cf3 = ((w ^ 1) == wp) ? dof : ddiag1;    // p=(1,1)

    const float sumr = m0r*cf0 + m1r*cf1 + m2r*cf2 + m3r*cf3;
    const float sumi = m0i*cf0 + m1i*cf1 + m2i*cf2 + m3i*cf3;

    // ufac = u_0[w] * conj(u_0[w'])
    const float uwr = w  ? a1r : a0r, uwi = w  ? a1i : a0i;
    const float upr = wp ? a1r : a0r, upi = wp ? a1i : a0i;
    const float ufr = uwr*upr + uwi*upi;
    const float ufi = uwi*upr - uwr*upi;

    float res = sumr*ufr - sumi*ufi;          // real part of row-r contribution
    res += __shfl_xor(res, 1, 64);
    res += __shfl_xor(res, 2, 64);
    if (r == 0) out[sample * 16 + q] = res;
  }
}

extern "C" void kernel_launch(void* const* d_in, const int* in_sizes, int n_in,
                              void* d_out, int out_size, void* d_ws, size_t ws_size,
                              hipStream_t stream) {
  (void)in_sizes; (void)n_in; (void)d_ws; (void)ws_size; (void)out_size;
  const float* x = (const float*)d_in[0];       // (512, 16) fp32
  const float* params = (const float*)d_in[1];  // (32,) fp32
  float* out = (float*)d_out;                   // (512, 16) fp32
  // 512 samples x 16 outputs x 4 rows = 32768 lanes = 128 blocks x 256 threads
  hipLaunchKernelGGL(qexp_kernel, dim3(128), dim3(256), 0, stream, x, params, out);
}